// Round 15
// baseline (91.269 us; speedup 1.0000x reference)
//
#include <hip/hip_runtime.h>

constexpr int HH = 100;
constexpr int WW = 100;
constexpr int NH = 8;
constexpr int NP = 4;
constexpr int B  = 4;
constexpr int Q  = HH * WW;   // 10000
constexpr int S  = Q;
constexpr int K  = 256;
constexpr int DH = 32;
constexpr int M  = B * Q;     // 40000
constexpr int NTILES = M / 32; // 1250

typedef __attribute__((ext_vector_type(8))) short short8;
typedef __attribute__((ext_vector_type(4))) float f32x4;

struct __align__(8) ushort4p { unsigned short x, y, z, w; };

__device__ inline unsigned short f2bf(float f) {
    unsigned u = __builtin_bit_cast(unsigned, f);
    u += 0x7fffu + ((u >> 16) & 1u);          // RNE
    return (unsigned short)(u >> 16);
}
__device__ inline float bf2f(unsigned short h) {
    return __builtin_bit_cast(float, ((unsigned)h) << 16);
}
__device__ inline unsigned short f2h(float f) {
    _Float16 h = (_Float16)f;
    return __builtin_bit_cast(unsigned short, h);
}
__device__ inline float h2f(unsigned short u) {
    return (float)__builtin_bit_cast(_Float16, u);
}

// LDS bf16 tile helpers (16B-chunk XOR swizzle: chunk ^= row&7).
__device__ inline void lds_st16s(short* base, int row, int stride, int kcol, short8 v) {
    *reinterpret_cast<short8*>(&base[row * stride + (kcol ^ ((row & 7) << 3))]) = v;
}
__device__ inline short8 lds_ld16s(const short* base, int row, int stride, int kcol) {
    return *reinterpret_cast<const short8*>(&base[row * stride + (kcol ^ ((row & 7) << 3))]);
}

__device__ inline short8 cvt8(float4 a, float4 b) {
    short8 r;
    r[0] = (short)f2bf(a.x); r[1] = (short)f2bf(a.y);
    r[2] = (short)f2bf(a.z); r[3] = (short)f2bf(a.w);
    r[4] = (short)f2bf(b.x); r[5] = (short)f2bf(b.y);
    r[6] = (short)f2bf(b.z); r[7] = (short)f2bf(b.w);
    return r;
}

#define GLDS(srcp, dstp) \
    __builtin_amdgcn_global_load_lds( \
        (const __attribute__((address_space(1))) unsigned int*)(srcp), \
        (__attribute__((address_space(3))) unsigned int*)(dstp), 16, 0, 0)

// ---------------------------------------------------------------------------
// Stage 1: value proj + off/attn proj, heterogeneous persistent launch.
// 256 blocks x 1024 thr. B in VGPRs (8x short8/lane). A staged as RAW F32 via
// global_load_lds into a 4-deep LDS multibuffer (4 x 32 KB = 128 KB): no
// register round-trip, no ds_write, counted vmcnt (never 0 in loop), raw
// s_barrier. cvt f32->bf16 on the consumer side. Swizzle: linear LDS dest,
// inverse-XOR per-lane SOURCE chunk (lane^(row&7)), same XOR on ds_read.
// Swapped-MFMA epilogue (round-14): lane owns 4 consecutive n -> packed store.
//   blocks 0..142   : enc @ W_val^T   -> vflat bf16
//   blocks 143..255 : hidden @ [W_off;W_attn]^T -> proj f16 [M][96]
// ---------------------------------------------------------------------------
__global__ __launch_bounds__(1024) void stage1(
    const float* __restrict__ enc, const float* __restrict__ Wval,
    const float* __restrict__ bval, unsigned short* __restrict__ vflat,
    const float* __restrict__ hidden, const float* __restrict__ Woff,
    const float* __restrict__ Wattn, const float* __restrict__ boff,
    const float* __restrict__ battn, unsigned short* __restrict__ proj)
{
    __shared__ __align__(16) float fbuf[4][32 * 256];   // 131072 B

    const int tid  = threadIdx.x;
    const int lane = tid & 63, w = tid >> 6;
    const int l15  = lane & 15, l4 = lane >> 4;

    constexpr int NV = 143, NJ = 113;

    // staging geometry: wave w stages tile rows 2w, 2w+1 (64 lanes x 16B = 1 row)
    const int r0 = 2 * w, r1 = 2 * w + 1;
    const int sc0 = lane ^ (r0 & 7);    // inverse-swizzled source chunk
    const int sc1 = lane ^ (r1 & 7);

    // f32 frag read: row r, k-step ks -> 8 f32 (two swizzled 16B chunks) -> bf16
    auto ldfrag = [&](const float* buf, int r, int ks) -> short8 {
        const int c0 = ks * 8 + l4 * 2;
        const float4 p0 = *reinterpret_cast<const float4*>(
            &buf[r * 256 + ((c0 ^ (r & 7)) << 2)]);
        const float4 p1 = *reinterpret_cast<const float4*>(
            &buf[r * 256 + (((c0 + 1) ^ (r & 7)) << 2)]);
        return cvt8(p0, p1);
    };

    if (blockIdx.x < NV) {
        // ---------------- value projection ----------------
        const int n = w * 16 + l15;          // lane's weight row
        short8 breg[8];
#pragma unroll
        for (int ks = 0; ks < 8; ++ks) {
            const float* s = &Wval[(size_t)n * K + ks * 32 + l4 * 8];
            breg[ks] = cvt8(*reinterpret_cast<const float4*>(s),
                            *reinterpret_cast<const float4*>(s + 4));
        }
        const int nbase = w * 16 + l4 * 4;   // output n-range (swapped MFMA)
        const float4 bias4 = *reinterpret_cast<const float4*>(&bval[nbase]);
        const int h = w >> 1;
        const int dd0 = nbase & 31;
        asm volatile("s_waitcnt vmcnt(0)" ::: "memory");  // retire weight loads

        auto stage = [&](int tt, int bi) {
            GLDS(enc + (size_t)(tt * 32 + r0) * K + sc0 * 4, &fbuf[bi][r0 * 256]);
            GLDS(enc + (size_t)(tt * 32 + r1) * K + sc1 * 4, &fbuf[bi][r1 * 256]);
        };

        int t = blockIdx.x;
        stage(t, 0);
        if (t + NV < NTILES) stage(t + NV, 1);
        if (t + 2 * NV < NTILES) stage(t + 2 * NV, 2);
        asm volatile("s_waitcnt vmcnt(4)\ns_barrier" ::: "memory");

        int bi = 0;
        for (; t < NTILES; t += NV, bi = (bi + 1) & 3) {
            const float* buf = fbuf[bi];
            f32x4 acc0 = {0.f, 0.f, 0.f, 0.f}, acc1 = {0.f, 0.f, 0.f, 0.f};
#pragma unroll
            for (int ks = 0; ks < 8; ++ks) {
                const short8 a0 = ldfrag(buf, l15, ks);
                const short8 a1 = ldfrag(buf, 16 + l15, ks);
                acc0 = __builtin_amdgcn_mfma_f32_16x16x32_bf16(breg[ks], a0, acc0, 0, 0, 0);
                acc1 = __builtin_amdgcn_mfma_f32_16x16x32_bf16(breg[ks], a1, acc1, 0, 0, 0);
            }
            const int m0 = t * 32;
            {
                const int m = m0 + l15;
                const int b_ = m / S, s_ = m - b_ * S;
                ushort4p pk;
                pk.x = f2bf(acc0[0] + bias4.x);
                pk.y = f2bf(acc0[1] + bias4.y);
                pk.z = f2bf(acc0[2] + bias4.z);
                pk.w = f2bf(acc0[3] + bias4.w);
                *reinterpret_cast<ushort4p*>(
                    &vflat[(((size_t)(b_ * NH + h)) * S + s_) * DH + dd0]) = pk;
            }
            {
                const int m = m0 + 16 + l15;
                const int b_ = m / S, s_ = m - b_ * S;
                ushort4p pk;
                pk.x = f2bf(acc1[0] + bias4.x);
                pk.y = f2bf(acc1[1] + bias4.y);
                pk.z = f2bf(acc1[2] + bias4.z);
                pk.w = f2bf(acc1[3] + bias4.w);
                *reinterpret_cast<ushort4p*>(
                    &vflat[(((size_t)(b_ * NH + h)) * S + s_) * DH + dd0]) = pk;
            }
            if (t + 3 * NV < NTILES) {
                stage(t + 3 * NV, (bi + 3) & 3);
                asm volatile("s_waitcnt vmcnt(4)\ns_barrier" ::: "memory");
            } else {
                asm volatile("s_waitcnt vmcnt(2)\ns_barrier" ::: "memory");
            }
        }
    } else {
        // ---------------- off+attn projection ----------------
        const int nf = w >> 1, mh = w & 1;   // waves 0..11 compute
        const int n = nf * 16 + l15;
        short8 breg[8];
        float4 bias4 = {0.f, 0.f, 0.f, 0.f};
        const int nbase = nf * 16 + l4 * 4;
        if (w < 12) {
#pragma unroll
            for (int ks = 0; ks < 8; ++ks) {
                const float* s = (n < 64)
                    ? &Woff[(size_t)n * K + ks * 32 + l4 * 8]
                    : &Wattn[(size_t)(n - 64) * K + ks * 32 + l4 * 8];
                breg[ks] = cvt8(*reinterpret_cast<const float4*>(s),
                                *reinterpret_cast<const float4*>(s + 4));
            }
            bias4 = (nf < 4)
                ? *reinterpret_cast<const float4*>(&boff[nbase])
                : *reinterpret_cast<const float4*>(&battn[nbase - 64]);
        }
        asm volatile("s_waitcnt vmcnt(0)" ::: "memory");

        auto stage = [&](int tt, int bi) {
            GLDS(hidden + (size_t)(tt * 32 + r0) * K + sc0 * 4, &fbuf[bi][r0 * 256]);
            GLDS(hidden + (size_t)(tt * 32 + r1) * K + sc1 * 4, &fbuf[bi][r1 * 256]);
        };

        int t = blockIdx.x - NV;
        stage(t, 0);
        if (t + NJ < NTILES) stage(t + NJ, 1);
        if (t + 2 * NJ < NTILES) stage(t + 2 * NJ, 2);
        asm volatile("s_waitcnt vmcnt(4)\ns_barrier" ::: "memory");

        int bi = 0;
        for (; t < NTILES; t += NJ, bi = (bi + 1) & 3) {
            const float* buf = fbuf[bi];
            if (w < 12) {
                f32x4 acc = {0.f, 0.f, 0.f, 0.f};
#pragma unroll
                for (int ks = 0; ks < 8; ++ks) {
                    const short8 a = ldfrag(buf, mh * 16 + l15, ks);
                    acc = __builtin_amdgcn_mfma_f32_16x16x32_bf16(breg[ks], a, acc, 0, 0, 0);
                }
                const int m = t * 32 + mh * 16 + l15;
                ushort4p pk;
                pk.x = f2h(acc[0] + bias4.x);
                pk.y = f2h(acc[1] + bias4.y);
                pk.z = f2h(acc[2] + bias4.z);
                pk.w = f2h(acc[3] + bias4.w);
                *reinterpret_cast<ushort4p*>(&proj[(size_t)m * 96 + nbase]) = pk;
            }
            if (t + 3 * NJ < NTILES) {
                stage(t + 3 * NJ, (bi + 3) & 3);
                asm volatile("s_waitcnt vmcnt(4)\ns_barrier" ::: "memory");
            } else {
                asm volatile("s_waitcnt vmcnt(2)\ns_barrier" ::: "memory");
            }
        }
    }
}

// ---------------------------------------------------------------------------
// Kernel S: bilinear sampling + attention aggregation (round-10 version).
// 4 lanes per (b,h,q) group; lane owns 8 d-elements (16B gathers).
// 64 groups per 256-thread block; 5000 blocks, XCD-swizzled.
// ---------------------------------------------------------------------------
__global__ __launch_bounds__(256) void sample_agg(
    const unsigned short* __restrict__ vflat,  // [B*NH][S][DH] bf16
    const unsigned short* __restrict__ proj,   // [M][96] f16
    const float* __restrict__ ref,             // [M][2]
    unsigned short* __restrict__ tmp)          // [M][256] bf16
{
    const int nblk = gridDim.x;                // 5000, %8 == 0
    const int cpx  = nblk >> 3;
    const int swz  = (blockIdx.x & 7) * cpx + (blockIdx.x >> 3);

    const int lg   = threadIdx.x >> 2;   // 0..63
    const int lane = threadIdx.x & 3;
    const int d0   = lane * 8;

    const int g  = swz * 64 + lg;
    const int q  = g % Q;
    const int bh = g / Q;
    const int b  = bh >> 3;
    const int h  = bh & 7;

    const size_t bq = (size_t)b * Q + q;
    const float refx = ref[bq * 2 + 0];
    const float refy = ref[bq * 2 + 1];
    const unsigned short* pr = proj + bq * 96;

    float l[NP];
#pragma unroll
    for (int p = 0; p < NP; ++p) l[p] = h2f(pr[64 + h * 4 + p]);
    const float mx = fmaxf(fmaxf(l[0], l[1]), fmaxf(l[2], l[3]));
    float e[NP];
    float esum = 0.f;
#pragma unroll
    for (int p = 0; p < NP; ++p) { e[p] = __expf(l[p] - mx); esum += e[p]; }
    const float inv = 1.f / esum;

    const unsigned short* vbase = vflat + (size_t)bh * (S * DH);

    int   cidx[NP][4];
    float cw[NP][4];
#pragma unroll
    for (int p = 0; p < NP; ++p) {
        const float ox = h2f(pr[h * 8 + p * 2 + 0]);
        const float oy = h2f(pr[h * 8 + p * 2 + 1]);
        const float x = fmaf(refx, (float)WW, ox) - 0.5f;
        const float y = fmaf(refy, (float)HH, oy) - 0.5f;
        const float x0f = floorf(x), y0f = floorf(y);
        const float wx1 = x - x0f, wx0 = 1.f - wx1;
        const float wy1 = y - y0f, wy0 = 1.f - wy1;
        const int x0 = (int)x0f, y0 = (int)y0f;
        const bool vx0 = (x0 >= 0) && (x0 < WW);
        const bool vx1 = (x0 + 1 >= 0) && (x0 + 1 < WW);
        const bool vy0 = (y0 >= 0) && (y0 < HH);
        const bool vy1 = (y0 + 1 >= 0) && (y0 + 1 < HH);
        const int xi0 = min(max(x0, 0), WW - 1);
        const int xi1 = min(max(x0 + 1, 0), WW - 1);
        const int yi0 = min(max(y0, 0), HH - 1);
        const int yi1 = min(max(y0 + 1, 0), HH - 1);
        const float ap = e[p] * inv;
        cw[p][0] = ap * wx0 * wy0 * ((vx0 && vy0) ? 1.f : 0.f);
        cw[p][1] = ap * wx1 * wy0 * ((vx1 && vy0) ? 1.f : 0.f);
        cw[p][2] = ap * wx0 * wy1 * ((vx0 && vy1) ? 1.f : 0.f);
        cw[p][3] = ap * wx1 * wy1 * ((vx1 && vy1) ? 1.f : 0.f);
        cidx[p][0] = (yi0 * WW + xi0) * DH + d0;
        cidx[p][1] = (yi0 * WW + xi1) * DH + d0;
        cidx[p][2] = (yi1 * WW + xi0) * DH + d0;
        cidx[p][3] = (yi1 * WW + xi1) * DH + d0;
    }

    float o[8];
#pragma unroll
    for (int j = 0; j < 8; ++j) o[j] = 0.f;
#pragma unroll
    for (int p = 0; p < NP; ++p) {
#pragma unroll
        for (int c = 0; c < 4; ++c) {
            const short8 v = *reinterpret_cast<const short8*>(&vbase[cidx[p][c]]);
            const float wgt = cw[p][c];
#pragma unroll
            for (int j = 0; j < 8; ++j)
                o[j] = fmaf(wgt, bf2f((unsigned short)v[j]), o[j]);
        }
    }

    short8 ov;
#pragma unroll
    for (int j = 0; j < 8; ++j) ov[j] = (short)f2bf(o[j]);
    *reinterpret_cast<short8*>(&tmp[bq * 256 + h * 32 + d0]) = ov;
}

// ---------------------------------------------------------------------------
// Kernel O: out projection. 256 blocks x 1024 thr, W in VGPRs.
// A (bf16) staged via global_load_lds into 4-deep multibuffer (4 x 16 KB),
// counted vmcnt + raw s_barrier. Swapped-MFMA f32x4 packed stores.
// ---------------------------------------------------------------------------
__global__ __launch_bounds__(1024) void out_proj(
    const unsigned short* __restrict__ tmp, const float* __restrict__ Wo,
    const float* __restrict__ bo, float* __restrict__ out)
{
    __shared__ __align__(16) short bbuf[4][32 * 256];   // 65536 B

    const int tid  = threadIdx.x;
    const int lane = tid & 63, w = tid >> 6;
    const int l15  = lane & 15, l4 = lane >> 4;

    const int n = w * 16 + l15;               // lane's weight row
    short8 breg[8];
#pragma unroll
    for (int ks = 0; ks < 8; ++ks) {
        const float* s = &Wo[(size_t)n * K + ks * 32 + l4 * 8];
        breg[ks] = cvt8(*reinterpret_cast<const float4*>(s),
                        *reinterpret_cast<const float4*>(s + 4));
    }
    const int nbase = w * 16 + l4 * 4;
    const float4 bias4 = *reinterpret_cast<const float4*>(&bo[nbase]);
    asm volatile("s_waitcnt vmcnt(0)" ::: "memory");

    // staging: wave w covers rows 2w, 2w+1 (bf16, 512B/row, 1 instr = 1 KB)
    const int srow = 2 * w + (lane >> 5);     // this lane's row
    const int schunk = (lane & 31) ^ (srow & 7);
    auto stage = [&](int tt, int bi) {
        GLDS(tmp + (size_t)(tt * 32 + srow) * K + schunk * 8, &bbuf[bi][w * 512]);
    };

    int t = blockIdx.x;
    stage(t, 0);
    if (t + 256 < NTILES) stage(t + 256, 1);
    if (t + 512 < NTILES) stage(t + 512, 2);
    asm volatile("s_waitcnt vmcnt(2)\ns_barrier" ::: "memory");

    int bi = 0;
    for (; t < NTILES; t += 256, bi = (bi + 1) & 3) {
        const short* buf = bbuf[bi];
        f32x4 acc0 = {0.f, 0.f, 0.f, 0.f}, acc1 = {0.f, 0.f, 0.f, 0.f};
#pragma unroll
        for (int ks = 0; ks < 8; ++ks) {
            const int kc = ks * 32 + l4 * 8;
            const short8 a0 = lds_ld16s(buf, l15, 256, kc);
            const short8 a1 = lds_ld16s(buf, 16 + l15, 256, kc);
            acc0 = __builtin_amdgcn_mfma_f32_16x16x32_bf16(breg[ks], a0, acc0, 0, 0, 0);
            acc1 = __builtin_amdgcn_mfma_f32_16x16x32_bf16(breg[ks], a1, acc1, 0, 0, 0);
        }
        const int m0 = t * 32;
        {
            const int m = m0 + l15;
            float4 pv;
            pv.x = acc0[0] + bias4.x; pv.y = acc0[1] + bias4.y;
            pv.z = acc0[2] + bias4.z; pv.w = acc0[3] + bias4.w;
            *reinterpret_cast<float4*>(&out[(size_t)m * K + nbase]) = pv;
        }
        {
            const int m = m0 + 16 + l15;
            float4 pv;
            pv.x = acc1[0] + bias4.x; pv.y = acc1[1] + bias4.y;
            pv.z = acc1[2] + bias4.z; pv.w = acc1[3] + bias4.w;
            *reinterpret_cast<float4*>(&out[(size_t)m * K + nbase]) = pv;
        }
        if (t + 768 < NTILES) {
            stage(t + 768, (bi + 3) & 3);
            asm volatile("s_waitcnt vmcnt(4)\ns_barrier" ::: "memory");
        } else {
            asm volatile("s_waitcnt vmcnt(2)\ns_barrier" ::: "memory");
        }
    }
}

// ---------------------------------------------------------------------------
extern "C" void kernel_launch(void* const* d_in, const int* in_sizes, int n_in,
                              void* d_out, int out_size, void* d_ws, size_t ws_size,
                              hipStream_t stream)
{
    const float* hidden = (const float*)d_in[0];
    const float* enc    = (const float*)d_in[1];
    const float* refp   = (const float*)d_in[2];
    const float* W_off  = (const float*)d_in[4];
    const float* b_off  = (const float*)d_in[5];
    const float* W_attn = (const float*)d_in[6];
    const float* b_attn = (const float*)d_in[7];
    const float* W_val  = (const float*)d_in[8];
    const float* b_val  = (const float*)d_in[9];
    const float* W_out  = (const float*)d_in[10];
    const float* b_out  = (const float*)d_in[11];
    float* out = (float*)d_out;

    // workspace (u16 elements): vflat | proj | tmp
    unsigned short* vflat = (unsigned short*)d_ws;     // 10,240,000
    unsigned short* proj  = vflat + (size_t)10240000;  //  3,840,000
    unsigned short* tmp   = proj + (size_t)3840000;    // 10,240,000

    // 1) value proj (143 blocks) + off/attn proj (113 blocks), glds pipeline
    stage1<<<256, 1024, 0, stream>>>(
        enc, W_val, b_val, vflat, hidden, W_off, W_attn, b_off, b_attn, proj);

    // 2) bilinear sampling + softmax aggregation -> tmp bf16 [M][256]
    sample_agg<<<5000, 256, 0, stream>>>(vflat, proj, refp, tmp);

    // 3) out projection (reg-B, glds 4-deep pipeline) -> f32
    out_proj<<<256, 1024, 0, stream>>>(tmp, W_out, b_out, out);
}